// Round 14
// baseline (163.211 us; speedup 1.0000x reference)
//
#include <hip/hip_runtime.h>

typedef unsigned short u16;
typedef unsigned int u32;
typedef __attribute__((ext_vector_type(4))) float f32x4;
typedef __attribute__((ext_vector_type(16))) float f32x16;
typedef __attribute__((ext_vector_type(8))) short bf16x8;

constexpr int B_ = 2, T_ = 4096, S_ = 4096, G_ = 64, D_ = 1024, H_ = 16, W_ = 512, CHUNK_ = 256;
constexpr int NC_ = T_ / CHUNK_;    // 16 chunks
constexpr int NR_ = (G_ + W_) / 64; // 9 key ROUNDS of 64 (1 global + 8 window)

__device__ __forceinline__ u16 f2bf(float x) {
  u32 u = __builtin_bit_cast(u32, x);
  return (u16)((u + 0x7FFFu + ((u >> 16) & 1u)) >> 16);
}

// ---------------- fused f32 -> bf16 conversion (all 9 segments, one dispatch) ----------------
__global__ __launch_bounds__(256) void cvt_all_kernel(const float* __restrict__ q, const float* __restrict__ e,
                                                      const float* __restrict__ g, const float* __restrict__ w0,
                                                      const float* __restrict__ w1, const float* __restrict__ w2,
                                                      const float* __restrict__ w3, const float* __restrict__ w4,
                                                      const float* __restrict__ w5, u16* __restrict__ dst) {
  int blk = blockIdx.x;
  const float* src;
  int sblk;  // segment start block
  if (blk < 8192) { src = q; sblk = 0; }
  else if (blk < 16384) { src = e; sblk = 8192; }
  else if (blk < 16512) { src = g; sblk = 16384; }
  else if (blk < 17536) { src = w0; sblk = 16512; }
  else if (blk < 18560) { src = w1; sblk = 17536; }
  else if (blk < 19584) { src = w2; sblk = 18560; }
  else if (blk < 20608) { src = w3; sblk = 19584; }
  else if (blk < 21632) { src = w4; sblk = 20608; }
  else { src = w5; sblk = 21632; }
  int li = (blk - sblk) * 256 + threadIdx.x;        // float4 index within segment
  size_t gi = (size_t)blk * 256 + threadIdx.x;      // float4 index within concatenation
  float4 v = ((const float4*)src)[li];
  uint2 o;
  o.x = (u32)f2bf(v.x) | ((u32)f2bf(v.y) << 16);
  o.y = (u32)f2bf(v.z) | ((u32)f2bf(v.w) << 16);
  ((uint2*)dst)[gi] = o;
}

// ---------------- merged projection GEMM: Q + K|V + GK|GV (256x256, 32x32x16 MFMA) ----------------
// v14 = r13 (PASSED) with the inner product switched 16x16x32 -> 32x32x16: same 12 b128
// LDS reads per K-step feed 16 MFMAs (was 32) at the higher 32x32 rate (m119: 2495 vs
// ~2176 TF). Operand layouts cribbed from the harness-verified attn usage of this exact
// intrinsic: A row = l&31 / k = (l>>5)*8+e+16s; B col = l&31 same k; C/D col = l&31,
// row = (r&3)+8*(r>>2)+4*(l>>5). Swapped operands: weights = A-op (out-col dim in regs),
// activations = B-op (out-row = l31). Staging/ring/vmcnt/swizzle/routing unchanged.
__global__ __launch_bounds__(512, 2) void proj_kernel(const u16* __restrict__ ex, const u16* __restrict__ qx,
                                                      const u16* __restrict__ gx, const u16* __restrict__ wgt,
                                                      const float* __restrict__ qb, const float* __restrict__ kbias,
                                                      const float* __restrict__ vbias, const float* __restrict__ gkb,
                                                      const float* __restrict__ gvb, u16* __restrict__ q_bf,
                                                      u16* __restrict__ k_bf, u16* __restrict__ gk_bf) {
  __shared__ char lds[81920];  // A ring-2 [0,32768); B ring-3 [32768,81920)
  constexpr size_t NW = (size_t)D_ * D_;
  constexpr size_t NQs = (size_t)B_ * T_ * D_;
  constexpr size_t NGs = (size_t)B_ * G_ * D_;
  const int tid = threadIdx.x;
  const int lane = tid & 63;
  const int wid = tid >> 6;
  const int wm = wid >> 2, wn = wid & 3;  // wm 0..1 (128-row slabs), wn 0..3 (64-col slabs)
  const int l31 = lane & 31, khalf = lane >> 5;

  const int bid = blockIdx.x;
  const u16 *A, *Bt;
  const float *b1, *b2;
  u16* out;
  int row0, col0, mloc;
  bool scale = false, dual = false;
  size_t dsplit = 0;
  if (bid < 256) {  // K|V: M=8192, N=2048 -> 32 x 8 tiles
    row0 = (bid & 31) * 256; col0 = (bid >> 5) * 256; mloc = 256;
    A = ex; Bt = wgt + NW; b1 = kbias; b2 = vbias; out = k_bf; dsplit = NQs; dual = true;
  } else if (bid < 384) {  // Q: M=8192, N=1024 -> 32 x 4 tiles
    int i = bid - 256;
    row0 = (i & 31) * 256; col0 = (i >> 5) * 256; mloc = 256;
    A = qx; Bt = wgt; b1 = qb; b2 = qb; out = q_bf; scale = true;
  } else {  // GK|GV: M=128, N=2048 -> 8 col tiles (rows 128..255 read junk in-bounds, stores guarded)
    int i = bid - 384;
    row0 = 0; col0 = i * 256; mloc = 128;
    A = gx; Bt = wgt + 3 * NW; b1 = gkb; b2 = gvb; out = gk_bf; dsplit = NGs; dual = true;
  }
  const float* bp = b1;
  u16* op = out;
  if (dual && col0 >= 1024) { bp = b2 - 1024; op = out + (dsplit - 1024); }

  f32x16 acc[2][4];  // [cj: 32-col tile][ri: 32-row tile], per-wave 128 rows x 64 cols
#pragma unroll
  for (int i = 0; i < 2; i++)
#pragma unroll
    for (int j = 0; j < 4; j++)
#pragma unroll
      for (int r = 0; r < 16; r++) acc[i][j][r] = 0.f;

  const char* Abase = (const char*)A;
  const char* Bbase = (const char*)Bt;
  // source pre-swizzle: LDS[row][chunk c] holds logical chunk c ^ ((row>>1)&3)
  const int swb = 16 * ((tid & 3) ^ ((tid >> 3) & 3));

  auto stageA = [&](int slot, int kt) {
#pragma unroll
    for (int p = 0; p < 2; p++) {
      int dst = slot * 16384 + p * 8192 + tid * 16;
      const char* g = Abase + (size_t)(row0 + p * 128 + (tid >> 2)) * 2048 + kt * 64 + swb;
      __builtin_amdgcn_global_load_lds((const __attribute__((address_space(1))) void*)g,
                                       (__attribute__((address_space(3))) void*)(lds + dst), 16, 0, 0);
    }
  };
  auto stageB = [&](int slot, int kt) {
#pragma unroll
    for (int p = 0; p < 2; p++) {
      int dst = 32768 + slot * 16384 + p * 8192 + tid * 16;
      const char* g = Bbase + (size_t)(col0 + p * 128 + (tid >> 2)) * 2048 + kt * 64 + swb;
      __builtin_amdgcn_global_load_lds((const __attribute__((address_space(1))) void*)g,
                                       (__attribute__((address_space(3))) void*)(lds + dst), 16, 0, 0);
    }
  };

  // prologue: A0, B0, B1 (6 loads); vmcnt(2) -> A0+B0 landed (newest 2 = B1)
  stageA(0, 0);
  stageB(0, 0);
  stageB(1, 1);
  asm volatile("s_waitcnt vmcnt(2)" ::: "memory");
  __builtin_amdgcn_s_barrier();

  for (int t = 0; t < 32; ++t) {
    if (t + 1 < 32) stageA((t + 1) & 1, t + 1);
    if (t + 2 < 32) stageB((t + 2) % 3, t + 2);
    const char* Ab = lds + (t & 1) * 16384;
    const char* Bb = lds + 32768 + (t % 3) * 16384;
    // frags: byte offset in row = s*32 + khalf*16 (k = khalf*8+e+16s), XOR-swizzled
    bf16x8 wf[2][2], xf[4][2];
#pragma unroll
    for (int cj = 0; cj < 2; cj++)
#pragma unroll
      for (int s = 0; s < 2; s++) {
        int r = wn * 64 + cj * 32 + l31;
        wf[cj][s] = *(const bf16x8*)(Bb + ((r * 64 + s * 32 + khalf * 16) ^ (((r >> 1) & 3) << 4)));
      }
#pragma unroll
    for (int ri = 0; ri < 4; ri++)
#pragma unroll
      for (int s = 0; s < 2; s++) {
        int r = wm * 128 + ri * 32 + l31;
        xf[ri][s] = *(const bf16x8*)(Ab + ((r * 64 + s * 32 + khalf * 16) ^ (((r >> 1) & 3) << 4)));
      }
    __builtin_amdgcn_s_setprio(1);
#pragma unroll
    for (int s = 0; s < 2; s++)
#pragma unroll
      for (int cj = 0; cj < 2; cj++)
#pragma unroll
        for (int ri = 0; ri < 4; ri++)
          acc[cj][ri] = __builtin_amdgcn_mfma_f32_32x32x16_bf16(wf[cj][s], xf[ri][s], acc[cj][ri], 0, 0, 0);
    __builtin_amdgcn_s_setprio(0);
    // boundary: A(t+1), B(t+1) landed; only B(t+2)'s 2 may remain in flight
    if (t < 30) {
      asm volatile("s_waitcnt vmcnt(2)" ::: "memory");
    } else if (t == 30) {
      asm volatile("s_waitcnt vmcnt(0)" ::: "memory");
    }
    __builtin_amdgcn_s_barrier();
  }

  // epilogue: lane holds C[out_row = row0+wm*128+ri*32+l31][out_col = col0+wn*64+cj*32+
  //           a*8+khalf*4 + (0..3)] in acc[cj][ri][4a..4a+3]; store guarded by mloc.
#pragma unroll
  for (int ri = 0; ri < 4; ri++) {
    int rloc = wm * 128 + ri * 32 + l31;
    if (rloc >= mloc) continue;  // wave-uniform (mloc=128 cuts exactly wm==1)
    size_t grow = (size_t)(row0 + rloc);
#pragma unroll
    for (int cj = 0; cj < 2; cj++) {
#pragma unroll
      for (int a = 0; a < 4; a++) {
        int gcol = col0 + wn * 64 + cj * 32 + a * 8 + khalf * 4;
        float4 bv = *(const float4*)&bp[gcol];
        float v0 = acc[cj][ri][4 * a + 0] + bv.x;
        float v1 = acc[cj][ri][4 * a + 1] + bv.y;
        float v2 = acc[cj][ri][4 * a + 2] + bv.z;
        float v3 = acc[cj][ri][4 * a + 3] + bv.w;
        if (scale) {
          v0 *= 0.18033688011112042f; v1 *= 0.18033688011112042f;  // (1/8)*log2(e)
          v2 *= 0.18033688011112042f; v3 *= 0.18033688011112042f;
        }
        uint2 o;
        asm("v_cvt_pk_bf16_f32 %0, %1, %2" : "=v"(o.x) : "v"(v0), "v"(v1));
        asm("v_cvt_pk_bf16_f32 %0, %1, %2" : "=v"(o.y) : "v"(v2), "v"(v3));
        *(uint2*)&op[grow * 1024 + gcol] = o;
      }
    }
  }
}

// ---------------- O-projection GEMM: r8 protocol + 32x32x16 MFMA, f32 epilogue ----------------
// M=8192, N=1024 -> 256 blocks; per-wave 64x64 = 2x2 tiles of 32x32, acc[2][2] f32x16.
__global__ __launch_bounds__(512, 2) void gemmO_kernel(const u16* __restrict__ A, const u16* __restrict__ Bt,
                                                       const float* __restrict__ bias, float* __restrict__ out) {
  __shared__ char lds[73728];  // A ring-3 [0,49152); B ring-3 [49152,73728)
  const int tid = threadIdx.x;
  const int lane = tid & 63;
  const int wid = tid >> 6;
  const int wm = wid >> 1, wn = wid & 1;
  const int l31 = lane & 31, khalf = lane >> 5;

  const int bid = blockIdx.x;
  const int row0 = (bid & 31) * 256;
  const int col0 = (bid >> 5) * 128;

  f32x16 acc[2][2];
#pragma unroll
  for (int i = 0; i < 2; i++)
#pragma unroll
    for (int j = 0; j < 2; j++)
#pragma unroll
      for (int r = 0; r < 16; r++) acc[i][j][r] = 0.f;

  const char* Abase = (const char*)A;
  const char* Bbase = (const char*)Bt;
  const int swb = 16 * ((tid & 3) ^ ((tid >> 3) & 3));

  auto stageA = [&](int slot, int kt) {
#pragma unroll
    for (int p = 0; p < 2; p++) {
      int dst = slot * 16384 + p * 8192 + tid * 16;
      const char* g = Abase + (size_t)(row0 + p * 128 + (tid >> 2)) * 2048 + kt * 64 + swb;
      __builtin_amdgcn_global_load_lds((const __attribute__((address_space(1))) void*)g,
                                       (__attribute__((address_space(3))) void*)(lds + dst), 16, 0, 0);
    }
  };
  auto stageB = [&](int slot, int kt) {
    int dst = 49152 + slot * 8192 + tid * 16;
    const char* g = Bbase + (size_t)(col0 + (tid >> 2)) * 2048 + kt * 64 + swb;
    __builtin_amdgcn_global_load_lds((const __attribute__((address_space(1))) void*)g,
                                     (__attribute__((address_space(3))) void*)(lds + dst), 16, 0, 0);
  };

  stageA(0, 0); stageB(0, 0);
  stageA(1, 1); stageB(1, 1);
  asm volatile("s_waitcnt vmcnt(3)" ::: "memory");
  __builtin_amdgcn_s_barrier();

  int cur = 0, nx = 2;
  for (int t = 0; t < 32; ++t) {
    const char* Ab = lds + cur * 16384;
    const char* Bb = lds + 49152 + cur * 8192;
    if (t + 2 < 32) { stageA(nx, t + 2); stageB(nx, t + 2); }
    bf16x8 wf[2][2], xf[2][2];
#pragma unroll
    for (int cj = 0; cj < 2; cj++)
#pragma unroll
      for (int s = 0; s < 2; s++) {
        int r = wn * 64 + cj * 32 + l31;
        wf[cj][s] = *(const bf16x8*)(Bb + ((r * 64 + s * 32 + khalf * 16) ^ (((r >> 1) & 3) << 4)));
      }
#pragma unroll
    for (int ri = 0; ri < 2; ri++)
#pragma unroll
      for (int s = 0; s < 2; s++) {
        int r = wm * 64 + ri * 32 + l31;
        xf[ri][s] = *(const bf16x8*)(Ab + ((r * 64 + s * 32 + khalf * 16) ^ (((r >> 1) & 3) << 4)));
      }
    __builtin_amdgcn_s_setprio(1);
#pragma unroll
    for (int s = 0; s < 2; s++)
#pragma unroll
      for (int cj = 0; cj < 2; cj++)
#pragma unroll
        for (int ri = 0; ri < 2; ri++)
          acc[cj][ri] = __builtin_amdgcn_mfma_f32_32x32x16_bf16(wf[cj][s], xf[ri][s], acc[cj][ri], 0, 0, 0);
    __builtin_amdgcn_s_setprio(0);
    if (t < 30) {
      asm volatile("s_waitcnt vmcnt(3)" ::: "memory");
    } else if (t == 30) {
      asm volatile("s_waitcnt vmcnt(0)" ::: "memory");
    }
    __builtin_amdgcn_s_barrier();
    cur = cur == 2 ? 0 : cur + 1;
    nx = nx == 2 ? 0 : nx + 1;
  }

#pragma unroll
  for (int ri = 0; ri < 2; ri++) {
    size_t grow = (size_t)(row0 + wm * 64 + ri * 32 + l31);
#pragma unroll
    for (int cj = 0; cj < 2; cj++) {
#pragma unroll
      for (int a = 0; a < 4; a++) {
        int gcol = col0 + wn * 64 + cj * 32 + a * 8 + khalf * 4;
        float4 bv = *(const float4*)&bias[gcol];
        float4 fo;
        fo.x = acc[cj][ri][4 * a + 0] + bv.x;
        fo.y = acc[cj][ri][4 * a + 1] + bv.y;
        fo.z = acc[cj][ri][4 * a + 2] + bv.z;
        fo.w = acc[cj][ri][4 * a + 3] + bv.w;
        *(float4*)&out[grow * 1024 + gcol] = fo;
      }
    }
  }
}

// ---------------- fused attention: KVBLK=64 rounds (r12-verified, unchanged) ----------------
__global__ __launch_bounds__(512, 4) void attn_kernel(const u16* __restrict__ q_bf, const u16* __restrict__ k_bf,
                                                      const u16* __restrict__ v_bf, const u16* __restrict__ gk_bf,
                                                      const u16* __restrict__ gv_bf, u16* __restrict__ ao,
                                                      const int* __restrict__ rptr) {
  __shared__ u16 smem[18688];  // 37376 bytes
  const int c = blockIdx.x, h = blockIdx.y, b = blockIdx.z;
  const int tid = threadIdx.x;
  const int lane = tid & 63, wv = tid >> 6;
  const int l31 = lane & 31, half = lane >> 5;
  const int t0 = c * CHUNK_;

  int rr = rptr[0];
  int centert = c * CHUNK_ + CHUNK_ / 2;
  int expected = (int)((float)centert / (float)rr);
  expected = min(max(expected, 0), S_ - 1);
  int ws0 = min(max(expected - W_ / 2, 0), S_ - W_);

  bf16x8 qf[4];
  {
    const u16* qrow = q_bf + ((size_t)(b * T_ + t0 + wv * 32 + l31)) * D_ + h * 64 + half * 8;
#pragma unroll
    for (int s = 0; s < 4; s++) qf[s] = *(const bf16x8*)(qrow + s * 16);
  }

  const int key64 = tid >> 3, hq = tid & 7;
  const int ksub = key64 >> 5, k5 = key64 & 31;

  auto load_pair = [&](int r, uint4& kk, uint4& vvv) {
    const u16 *kb, *vb;
    size_t row;
    if (r == 0) {
      kb = gk_bf; vb = gv_bf;
      row = (size_t)(b * G_ + key64);
    } else {
      kb = k_bf; vb = v_bf;
      row = (size_t)(b * S_ + ws0 + (r - 1) * 64 + key64);
    }
    kk = *(const uint4*)(kb + row * D_ + h * 64 + hq * 8);
    vvv = *(const uint4*)(vb + row * D_ + h * 64 + hq * 8);
  };

  f32x16 oacc[2];
#pragma unroll
  for (int i = 0; i < 2; i++)
#pragma unroll
    for (int r = 0; r < 16; r++) oacc[i][r] = 0.f;
  float mrun = -1e30f, lsum = 0.f;

  uint4 stgK, stgV;
  load_pair(0, stgK, stgV);

  for (int rd = 0; rd < NR_; rd++) {
    const int bsel = rd & 1;
    *(uint4*)((char*)smem + bsel * 8192 + ksub * 4096 + ((k5 * 128 + hq * 16) ^ ((k5 & 7) << 4))) = stgK;
    {
      const u16* pv = (const u16*)&stgV;
      char* bp = (char*)smem + 16384 + bsel * 10496 + ksub * 5248 + hq * 656 + k5 * 2;  // 656 = 8*80+16
#pragma unroll
      for (int e = 0; e < 8; e++) *(u16*)(bp + e * 80) = pv[e];
    }
    if (rd + 1 < NR_) load_pair(rd + 1, stgK, stgV);
    __syncthreads();

#pragma unroll
    for (int sub = 0; sub < 2; sub++) {
      const int kbase = bsel * 8192 + sub * 4096;
      const int vtb = 16384 + bsel * 10496 + sub * 5248;

      f32x16 sacc;
#pragma unroll
      for (int r = 0; r < 16; r++) sacc[r] = 0.f;
      __builtin_amdgcn_s_setprio(1);
#pragma unroll
      for (int s = 0; s < 4; s++) {
        int kbx = kbase + ((l31 * 128 + half * 16 + s * 32) ^ ((l31 & 7) << 4));
        bf16x8 kf = *(const bf16x8*)((char*)smem + kbx);
        sacc = __builtin_amdgcn_mfma_f32_32x32x16_bf16(kf, qf[s], sacc, 0, 0, 0);
      }
      __builtin_amdgcn_s_setprio(0);

      float t0m = fmaxf(fmaxf(sacc[0], sacc[1]), sacc[2]);
      float t1m = fmaxf(fmaxf(sacc[3], sacc[4]), sacc[5]);
      float t2m = fmaxf(fmaxf(sacc[6], sacc[7]), sacc[8]);
      float t3m = fmaxf(fmaxf(sacc[9], sacc[10]), sacc[11]);
      float t4m = fmaxf(fmaxf(sacc[12], sacc[13]), sacc[14]);
      float tmax = fmaxf(fmaxf(fmaxf(t0m, t1m), fmaxf(t2m, t3m)), fmaxf(t4m, sacc[15]));
      tmax = fmaxf(tmax, __shfl_xor(tmax, 32));
      if (__any(tmax > mrun + 8.f)) {
        float mnew = fmaxf(mrun, tmax);
        float fac = __builtin_amdgcn_exp2f(mrun - mnew);
        mrun = mnew;
        lsum *= fac;
#pragma unroll
        for (int i = 0; i < 2; i++)
#pragma unroll
          for (int r = 0; r < 16; r++) oacc[i][r] *= fac;
      }
      float p[16];
#pragma unroll
      for (int r = 0; r < 16; r++) p[r] = __builtin_amdgcn_exp2f(sacc[r] - mrun);
      float s0s = (p[0] + p[1]) + (p[2] + p[3]);
      float s1s = (p[4] + p[5]) + (p[6] + p[7]);
      float s2s = (p[8] + p[9]) + (p[10] + p[11]);
      float s3s = (p[12] + p[13]) + (p[14] + p[15]);
      float tsum = (s0s + s1s) + (s2s + s3s);
      tsum += __shfl_xor(tsum, 32);
      lsum += tsum;

      u32 xs[8], px[8];
#pragma unroll
      for (int i = 0; i < 8; i++)
        asm("v_cvt_pk_bf16_f32 %0, %1, %2" : "=v"(xs[i]) : "v"(p[2 * i]), "v"(p[2 * i + 1]));
#pragma unroll
      for (int i = 0; i < 8; i++) px[i] = (u32)__shfl_xor((int)xs[i], 32);
      u32 Bk[2][4];
      Bk[0][0] = half ? px[2] : xs[0];
      Bk[0][1] = half ? px[3] : xs[1];
      Bk[0][2] = half ? xs[2] : px[0];
      Bk[0][3] = half ? xs[3] : px[1];
      Bk[1][0] = half ? px[6] : xs[4];
      Bk[1][1] = half ? px[7] : xs[5];
      Bk[1][2] = half ? xs[6] : px[4];
      Bk[1][3] = half ? xs[7] : px[5];

      int vro = vtb + l31 * 80 + ((l31 >> 3) << 4) + half * 16;
      __builtin_amdgcn_s_setprio(1);
#pragma unroll
      for (int hdf = 0; hdf < 2; hdf++) {
#pragma unroll
        for (int ks = 0; ks < 2; ks++) {
          bf16x8 vf = *(const bf16x8*)((const char*)smem + vro + hdf * 2624 + ks * 32);  // 2624 = 32*80+64
          uint4 u4;
          u4.x = Bk[ks][0]; u4.y = Bk[ks][1]; u4.z = Bk[ks][2]; u4.w = Bk[ks][3];
          bf16x8 pb = __builtin_bit_cast(bf16x8, u4);
          oacc[hdf] = __builtin_amdgcn_mfma_f32_32x32x16_bf16(vf, pb, oacc[hdf], 0, 0, 0);
        }
      }
      __builtin_amdgcn_s_setprio(0);
    }
  }

  __syncthreads();
  float inv = 1.f / lsum;
#pragma unroll
  for (int hdf = 0; hdf < 2; hdf++) {
#pragma unroll
    for (int a = 0; a < 4; a++) {
      float f0 = oacc[hdf][4 * a] * inv, f1 = oacc[hdf][4 * a + 1] * inv;
      float f2 = oacc[hdf][4 * a + 2] * inv, f3 = oacc[hdf][4 * a + 3] * inv;
      uint2 o;
      asm("v_cvt_pk_bf16_f32 %0, %1, %2" : "=v"(o.x) : "v"(f0), "v"(f1));
      asm("v_cvt_pk_bf16_f32 %0, %1, %2" : "=v"(o.y) : "v"(f2), "v"(f3));
      int off = wv * 4096 + l31 * 128 + ((16 * a + 8 * half + 64 * hdf) ^ ((l31 & 7) << 4));
      *(uint2*)((char*)smem + off) = o;
    }
  }
  __syncthreads();
#pragma unroll
  for (int it = 0; it < 4; it++) {
    int byteo = (tid + it * 512) * 16;
    int row = byteo >> 7;
    int colb = byteo & 127;
    uint4 vvv = *(const uint4*)((const char*)smem + row * 128 + (colb ^ ((row & 7) << 4)));
    *(uint4*)(ao + ((size_t)(b * T_ + t0 + row)) * D_ + h * 64 + (colb >> 1)) = vvv;
  }
}

extern "C" void kernel_launch(void* const* d_in, const int* in_sizes, int n_in,
                              void* d_out, int out_size, void* d_ws, size_t ws_size,
                              hipStream_t stream) {
  (void)in_sizes; (void)n_in; (void)out_size; (void)ws_size;
  const float* query = (const float*)d_in[0];
  const float* enc = (const float*)d_in[1];
  const float* glob = (const float*)d_in[2];
  const float* qw = (const float*)d_in[3];
  const float* qb = (const float*)d_in[4];
  const float* kw = (const float*)d_in[5];
  const float* kb = (const float*)d_in[6];
  const float* vw = (const float*)d_in[7];
  const float* vb = (const float*)d_in[8];
  const float* gkw = (const float*)d_in[9];
  const float* gkb = (const float*)d_in[10];
  const float* gvw = (const float*)d_in[11];
  const float* gvb = (const float*)d_in[12];
  const float* ow = (const float*)d_in[13];
  const float* ob = (const float*)d_in[14];
  const int* rp = (const int*)d_in[15];

  const size_t NQ = (size_t)B_ * T_ * D_;   // 8388608
  const size_t NG = (size_t)B_ * G_ * D_;   // 131072
  const size_t NW = (size_t)D_ * D_;        // 1048576

  u16* ws = (u16*)d_ws;
  u16* qx = ws;                // bf16 query
  u16* ex = qx + NQ;           // bf16 encoder_out
  u16* gx = ex + NQ;           // bf16 global_tokens
  u16* wgt = gx + NG;          // 6 weights bf16 (qw,kw,vw,gkw,gvw,ow) — contiguous
  u16* q_bf = wgt + 6 * NW;    // projected q (pre-scaled by 0.125*log2e)
  u16* k_bf = q_bf + NQ;
  u16* v_bf = k_bf + NQ;       // contiguous after k_bf (fused K|V)
  u16* gk_bf = v_bf + NQ;
  u16* gv_bf = gk_bf + NG;     // contiguous after gk_bf (fused GK|GV)
  u16* ao = gv_bf + NG;        // attention output bf16 [B*T, D]

  // one fused conversion dispatch: 8192+8192+128+6*1024 = 22656 blocks
  cvt_all_kernel<<<22656, 256, 0, stream>>>(query, enc, glob, qw, kw, vw, gkw, gvw, ow, ws);

  // merged Q + K|V + GK|GV projection: 392 blocks, 32x32x16 MFMA
  proj_kernel<<<392, 512, 0, stream>>>(ex, qx, gx, wgt, qb, kb, vb, gkb, gvb, q_bf, k_bf, gk_bf);

  attn_kernel<<<dim3(NC_, H_, B_), 512, 0, stream>>>(q_bf, k_bf, v_bf, gk_bf, gv_bf, ao, rp);

  // O projection, 32x32x16 MFMA
  gemmO_kernel<<<256, 512, 0, stream>>>(ao, wgt + 5 * NW, ob, (float*)d_out);
}

// Round 15
// 149.008 us; speedup vs baseline: 1.0953x; 1.0953x over previous
//
#include <hip/hip_runtime.h>

typedef unsigned short u16;
typedef unsigned int u32;
typedef __attribute__((ext_vector_type(4))) float f32x4;
typedef __attribute__((ext_vector_type(16))) float f32x16;
typedef __attribute__((ext_vector_type(8))) short bf16x8;

constexpr int B_ = 2, T_ = 4096, S_ = 4096, G_ = 64, D_ = 1024, H_ = 16, W_ = 512, CHUNK_ = 256;
constexpr int NC_ = T_ / CHUNK_;    // 16 chunks
constexpr int NR_ = (G_ + W_) / 64; // 9 key ROUNDS of 64 (1 global + 8 window)

__device__ __forceinline__ u16 f2bf(float x) {
  u32 u = __builtin_bit_cast(u32, x);
  return (u16)((u + 0x7FFFu + ((u >> 16) & 1u)) >> 16);
}

// ---------------- fused f32 -> bf16 conversion (all 9 segments, one dispatch) ----------------
__global__ __launch_bounds__(256) void cvt_all_kernel(const float* __restrict__ q, const float* __restrict__ e,
                                                      const float* __restrict__ g, const float* __restrict__ w0,
                                                      const float* __restrict__ w1, const float* __restrict__ w2,
                                                      const float* __restrict__ w3, const float* __restrict__ w4,
                                                      const float* __restrict__ w5, u16* __restrict__ dst) {
  int blk = blockIdx.x;
  const float* src;
  int sblk;  // segment start block
  if (blk < 8192) { src = q; sblk = 0; }
  else if (blk < 16384) { src = e; sblk = 8192; }
  else if (blk < 16512) { src = g; sblk = 16384; }
  else if (blk < 17536) { src = w0; sblk = 16512; }
  else if (blk < 18560) { src = w1; sblk = 17536; }
  else if (blk < 19584) { src = w2; sblk = 18560; }
  else if (blk < 20608) { src = w3; sblk = 19584; }
  else if (blk < 21632) { src = w4; sblk = 20608; }
  else { src = w5; sblk = 21632; }
  int li = (blk - sblk) * 256 + threadIdx.x;        // float4 index within segment
  size_t gi = (size_t)blk * 256 + threadIdx.x;      // float4 index within concatenation
  float4 v = ((const float4*)src)[li];
  uint2 o;
  o.x = (u32)f2bf(v.x) | ((u32)f2bf(v.y) << 16);
  o.y = (u32)f2bf(v.z) | ((u32)f2bf(v.w) << 16);
  ((uint2*)dst)[gi] = o;
}

// ---------------- merged projection GEMM: Q + K|V + GK|GV (256x256, asymmetric ring) ----------------
// r13-verified (74.8 µs, conflicts 0). 16x16x32 MFMA (r14 lesson: 32x32's khalf-uniform
// read column is an INHERENT 4-way bank conflict in this 64B-row layout — only the 16x16
// pattern's kg-spread is bank-bijective). Tile 256x256 -> 392 blocks (one scheduling
// round); LDS = A ring-2 + B ring-3 = 80KB -> 2 blocks/CU; counted vmcnt(2) boundary.
__global__ __launch_bounds__(512, 2) void proj_kernel(const u16* __restrict__ ex, const u16* __restrict__ qx,
                                                      const u16* __restrict__ gx, const u16* __restrict__ wgt,
                                                      const float* __restrict__ qb, const float* __restrict__ kbias,
                                                      const float* __restrict__ vbias, const float* __restrict__ gkb,
                                                      const float* __restrict__ gvb, u16* __restrict__ q_bf,
                                                      u16* __restrict__ k_bf, u16* __restrict__ gk_bf) {
  __shared__ char lds[81920];  // A ring-2 [0,32768); B ring-3 [32768,81920)
  constexpr size_t NW = (size_t)D_ * D_;
  constexpr size_t NQs = (size_t)B_ * T_ * D_;
  constexpr size_t NGs = (size_t)B_ * G_ * D_;
  const int tid = threadIdx.x;
  const int lane = tid & 63;
  const int wid = tid >> 6;
  const int wm = wid >> 2, wn = wid & 3;  // wm 0..1 (128-row slabs), wn 0..3 (64-col slabs)
  const int l15 = lane & 15, kg = lane >> 4;

  const int bid = blockIdx.x;
  const u16 *A, *Bt;
  const float *b1, *b2;
  u16* out;
  int row0, col0, mloc;
  bool scale = false, dual = false;
  size_t dsplit = 0;
  if (bid < 256) {  // K|V: M=8192, N=2048 -> 32 x 8 tiles
    row0 = (bid & 31) * 256; col0 = (bid >> 5) * 256; mloc = 256;
    A = ex; Bt = wgt + NW; b1 = kbias; b2 = vbias; out = k_bf; dsplit = NQs; dual = true;
  } else if (bid < 384) {  // Q: M=8192, N=1024 -> 32 x 4 tiles
    int i = bid - 256;
    row0 = (i & 31) * 256; col0 = (i >> 5) * 256; mloc = 256;
    A = qx; Bt = wgt; b1 = qb; b2 = qb; out = q_bf; scale = true;
  } else {  // GK|GV: M=128, N=2048 -> 8 col tiles (rows 128..255 read junk in-bounds, stores guarded)
    int i = bid - 384;
    row0 = 0; col0 = i * 256; mloc = 128;
    A = gx; Bt = wgt + 3 * NW; b1 = gkb; b2 = gvb; out = gk_bf; dsplit = NGs; dual = true;
  }
  const float* bp = b1;
  u16* op = out;
  if (dual && col0 >= 1024) { bp = b2 - 1024; op = out + (dsplit - 1024); }

  f32x4 acc[8][4];
#pragma unroll
  for (int i = 0; i < 8; i++)
#pragma unroll
    for (int j = 0; j < 4; j++)
#pragma unroll
      for (int r = 0; r < 4; r++) acc[i][j][r] = 0.f;

  const char* Abase = (const char*)A;
  const char* Bbase = (const char*)Bt;
  // source pre-swizzle: LDS holds chunk (tid&3), logical chunk = (tid&3)^((row>>1)&3);
  // row = p*128 + (tid>>2) -> (row>>1)&3 = (tid>>3)&3 for both p.
  const int swb = 16 * ((tid & 3) ^ ((tid >> 3) & 3));

  auto stageA = [&](int slot, int kt) {
#pragma unroll
    for (int p = 0; p < 2; p++) {
      int dst = slot * 16384 + p * 8192 + tid * 16;
      const char* g = Abase + (size_t)(row0 + p * 128 + (tid >> 2)) * 2048 + kt * 64 + swb;
      __builtin_amdgcn_global_load_lds((const __attribute__((address_space(1))) void*)g,
                                       (__attribute__((address_space(3))) void*)(lds + dst), 16, 0, 0);
    }
  };
  auto stageB = [&](int slot, int kt) {
#pragma unroll
    for (int p = 0; p < 2; p++) {
      int dst = 32768 + slot * 16384 + p * 8192 + tid * 16;
      const char* g = Bbase + (size_t)(col0 + p * 128 + (tid >> 2)) * 2048 + kt * 64 + swb;
      __builtin_amdgcn_global_load_lds((const __attribute__((address_space(1))) void*)g,
                                       (__attribute__((address_space(3))) void*)(lds + dst), 16, 0, 0);
    }
  };

  // prologue: A0, B0, B1 (6 loads); vmcnt(2) -> A0+B0 landed (newest 2 = B1)
  stageA(0, 0);
  stageB(0, 0);
  stageB(1, 1);
  asm volatile("s_waitcnt vmcnt(2)" ::: "memory");
  __builtin_amdgcn_s_barrier();

  for (int t = 0; t < 32; ++t) {
    if (t + 1 < 32) stageA((t + 1) & 1, t + 1);
    if (t + 2 < 32) stageB((t + 2) % 3, t + 2);
    const char* Ab = lds + (t & 1) * 16384;
    const char* Bb = lds + 32768 + (t % 3) * 16384;
    bf16x8 bq[4], af[8];
#pragma unroll
    for (int ni = 0; ni < 4; ni++) {
      int r = wn * 64 + ni * 16 + l15;
      bq[ni] = *(const bf16x8*)(Bb + ((r * 64 + kg * 16) ^ (((r >> 1) & 3) << 4)));
    }
#pragma unroll
    for (int mi = 0; mi < 8; mi++) {
      int r = wm * 128 + mi * 16 + l15;
      af[mi] = *(const bf16x8*)(Ab + ((r * 64 + kg * 16) ^ (((r >> 1) & 3) << 4)));
    }
    __builtin_amdgcn_s_setprio(1);
#pragma unroll
    for (int mi = 0; mi < 8; mi++)
#pragma unroll
      for (int ni = 0; ni < 4; ni++)
        acc[mi][ni] = __builtin_amdgcn_mfma_f32_16x16x32_bf16(bq[ni], af[mi], acc[mi][ni], 0, 0, 0);
    __builtin_amdgcn_s_setprio(0);
    // boundary: A(t+1), B(t+1) landed; only B(t+2)'s 2 may remain in flight
    if (t < 30) {
      asm volatile("s_waitcnt vmcnt(2)" ::: "memory");
    } else if (t == 30) {
      asm volatile("s_waitcnt vmcnt(0)" ::: "memory");
    }
    __builtin_amdgcn_s_barrier();
  }

  // epilogue: C[row0+wm*128+mi*16+l15][col0+wn*64+ni*16+kg*4+r], store guarded by mloc
  float4 bv4[4];
#pragma unroll
  for (int ni = 0; ni < 4; ni++) bv4[ni] = *(const float4*)&bp[col0 + wn * 64 + ni * 16 + kg * 4];
#pragma unroll
  for (int mi = 0; mi < 8; mi++) {
    int rloc = wm * 128 + mi * 16 + l15;
    if (rloc >= mloc) continue;  // wave-uniform (mloc=128 cuts exactly wm==1)
    size_t grow = (size_t)(row0 + rloc);
#pragma unroll
    for (int ni = 0; ni < 4; ni++) {
      int gcol = col0 + wn * 64 + ni * 16 + kg * 4;
      float v0 = acc[mi][ni][0] + bv4[ni].x;
      float v1 = acc[mi][ni][1] + bv4[ni].y;
      float v2 = acc[mi][ni][2] + bv4[ni].z;
      float v3 = acc[mi][ni][3] + bv4[ni].w;
      if (scale) {
        v0 *= 0.18033688011112042f; v1 *= 0.18033688011112042f;  // (1/8)*log2(e)
        v2 *= 0.18033688011112042f; v3 *= 0.18033688011112042f;
      }
      uint2 o;
      asm("v_cvt_pk_bf16_f32 %0, %1, %2" : "=v"(o.x) : "v"(v0), "v"(v1));
      asm("v_cvt_pk_bf16_f32 %0, %1, %2" : "=v"(o.y) : "v"(v2), "v"(v3));
      *(uint2*)&op[grow * 1024 + gcol] = o;
    }
  }
}

// ---------------- O-projection GEMM (r8/r11-verified, unchanged) ----------------
__global__ __launch_bounds__(512, 2) void gemmO_kernel(const u16* __restrict__ A, const u16* __restrict__ Bt,
                                                       const float* __restrict__ bias, float* __restrict__ out) {
  __shared__ char lds[73728];
  const int tid = threadIdx.x;
  const int lane = tid & 63;
  const int wid = tid >> 6;
  const int wm = wid >> 1, wn = wid & 1;
  const int l15 = lane & 15, kg = lane >> 4;

  const int bid = blockIdx.x;
  const int row0 = (bid & 31) * 256;
  const int col0 = (bid >> 5) * 128;

  f32x4 acc[4][4];
#pragma unroll
  for (int i = 0; i < 4; i++)
#pragma unroll
    for (int j = 0; j < 4; j++)
#pragma unroll
      for (int r = 0; r < 4; r++) acc[i][j][r] = 0.f;

  const char* Abase = (const char*)A;
  const char* Bbase = (const char*)Bt;
  const int swb = 16 * ((tid & 3) ^ ((tid >> 3) & 3));

  auto stageA = [&](int slot, int kt) {
#pragma unroll
    for (int p = 0; p < 2; p++) {
      int dst = slot * 16384 + p * 8192 + tid * 16;
      const char* g = Abase + (size_t)(row0 + p * 128 + (tid >> 2)) * 2048 + kt * 64 + swb;
      __builtin_amdgcn_global_load_lds((const __attribute__((address_space(1))) void*)g,
                                       (__attribute__((address_space(3))) void*)(lds + dst), 16, 0, 0);
    }
  };
  auto stageB = [&](int slot, int kt) {
    int dst = 49152 + slot * 8192 + tid * 16;
    const char* g = Bbase + (size_t)(col0 + (tid >> 2)) * 2048 + kt * 64 + swb;
    __builtin_amdgcn_global_load_lds((const __attribute__((address_space(1))) void*)g,
                                     (__attribute__((address_space(3))) void*)(lds + dst), 16, 0, 0);
  };

  stageA(0, 0); stageB(0, 0);
  stageA(1, 1); stageB(1, 1);
  asm volatile("s_waitcnt vmcnt(3)" ::: "memory");
  __builtin_amdgcn_s_barrier();

  int cur = 0, nx = 2;
  for (int t = 0; t < 32; ++t) {
    const char* Ab = lds + cur * 16384;
    const char* Bb = lds + 49152 + cur * 8192;
    if (t + 2 < 32) { stageA(nx, t + 2); stageB(nx, t + 2); }
    bf16x8 bq[4], af[4];
#pragma unroll
    for (int ni = 0; ni < 4; ni++) {
      int r = wn * 64 + ni * 16 + l15;
      bq[ni] = *(const bf16x8*)(Bb + ((r * 64 + kg * 16) ^ (((r >> 1) & 3) << 4)));
    }
#pragma unroll
    for (int mi = 0; mi < 4; mi++) {
      int r = wm * 64 + mi * 16 + l15;
      af[mi] = *(const bf16x8*)(Ab + ((r * 64 + kg * 16) ^ (((r >> 1) & 3) << 4)));
    }
    __builtin_amdgcn_s_setprio(1);
#pragma unroll
    for (int mi = 0; mi < 4; mi++)
#pragma unroll
      for (int ni = 0; ni < 4; ni++)
        acc[mi][ni] = __builtin_amdgcn_mfma_f32_16x16x32_bf16(bq[ni], af[mi], acc[mi][ni], 0, 0, 0);
    __builtin_amdgcn_s_setprio(0);
    if (t < 30) {
      asm volatile("s_waitcnt vmcnt(3)" ::: "memory");
    } else if (t == 30) {
      asm volatile("s_waitcnt vmcnt(0)" ::: "memory");
    }
    __builtin_amdgcn_s_barrier();
    cur = cur == 2 ? 0 : cur + 1;
    nx = nx == 2 ? 0 : nx + 1;
  }

  float4 bv4[4];
#pragma unroll
  for (int ni = 0; ni < 4; ni++) bv4[ni] = *(const float4*)&bias[col0 + wn * 64 + ni * 16 + kg * 4];
#pragma unroll
  for (int mi = 0; mi < 4; mi++) {
    size_t grow = (size_t)(row0 + wm * 64 + mi * 16 + l15);
#pragma unroll
    for (int ni = 0; ni < 4; ni++) {
      int gcol = col0 + wn * 64 + ni * 16 + kg * 4;
      float4 fo;
      fo.x = acc[mi][ni][0] + bv4[ni].x;
      fo.y = acc[mi][ni][1] + bv4[ni].y;
      fo.z = acc[mi][ni][2] + bv4[ni].z;
      fo.w = acc[mi][ni][3] + bv4[ni].w;
      *(float4*)&out[grow * 1024 + gcol] = fo;
    }
  }
}

// ---------------- fused attention: KVBLK=64 rounds (r12-verified, unchanged) ----------------
__global__ __launch_bounds__(512, 4) void attn_kernel(const u16* __restrict__ q_bf, const u16* __restrict__ k_bf,
                                                      const u16* __restrict__ v_bf, const u16* __restrict__ gk_bf,
                                                      const u16* __restrict__ gv_bf, u16* __restrict__ ao,
                                                      const int* __restrict__ rptr) {
  __shared__ u16 smem[18688];  // 37376 bytes
  const int c = blockIdx.x, h = blockIdx.y, b = blockIdx.z;
  const int tid = threadIdx.x;
  const int lane = tid & 63, wv = tid >> 6;
  const int l31 = lane & 31, half = lane >> 5;
  const int t0 = c * CHUNK_;

  int rr = rptr[0];
  int centert = c * CHUNK_ + CHUNK_ / 2;
  int expected = (int)((float)centert / (float)rr);
  expected = min(max(expected, 0), S_ - 1);
  int ws0 = min(max(expected - W_ / 2, 0), S_ - W_);

  bf16x8 qf[4];
  {
    const u16* qrow = q_bf + ((size_t)(b * T_ + t0 + wv * 32 + l31)) * D_ + h * 64 + half * 8;
#pragma unroll
    for (int s = 0; s < 4; s++) qf[s] = *(const bf16x8*)(qrow + s * 16);
  }

  const int key64 = tid >> 3, hq = tid & 7;
  const int ksub = key64 >> 5, k5 = key64 & 31;

  auto load_pair = [&](int r, uint4& kk, uint4& vvv) {
    const u16 *kb, *vb;
    size_t row;
    if (r == 0) {
      kb = gk_bf; vb = gv_bf;
      row = (size_t)(b * G_ + key64);
    } else {
      kb = k_bf; vb = v_bf;
      row = (size_t)(b * S_ + ws0 + (r - 1) * 64 + key64);
    }
    kk = *(const uint4*)(kb + row * D_ + h * 64 + hq * 8);
    vvv = *(const uint4*)(vb + row * D_ + h * 64 + hq * 8);
  };

  f32x16 oacc[2];
#pragma unroll
  for (int i = 0; i < 2; i++)
#pragma unroll
    for (int r = 0; r < 16; r++) oacc[i][r] = 0.f;
  float mrun = -1e30f, lsum = 0.f;

  uint4 stgK, stgV;
  load_pair(0, stgK, stgV);

  for (int rd = 0; rd < NR_; rd++) {
    const int bsel = rd & 1;
    *(uint4*)((char*)smem + bsel * 8192 + ksub * 4096 + ((k5 * 128 + hq * 16) ^ ((k5 & 7) << 4))) = stgK;
    {
      const u16* pv = (const u16*)&stgV;
      char* bp = (char*)smem + 16384 + bsel * 10496 + ksub * 5248 + hq * 656 + k5 * 2;  // 656 = 8*80+16
#pragma unroll
      for (int e = 0; e < 8; e++) *(u16*)(bp + e * 80) = pv[e];
    }
    if (rd + 1 < NR_) load_pair(rd + 1, stgK, stgV);
    __syncthreads();

#pragma unroll
    for (int sub = 0; sub < 2; sub++) {
      const int kbase = bsel * 8192 + sub * 4096;
      const int vtb = 16384 + bsel * 10496 + sub * 5248;

      f32x16 sacc;
#pragma unroll
      for (int r = 0; r < 16; r++) sacc[r] = 0.f;
      __builtin_amdgcn_s_setprio(1);
#pragma unroll
      for (int s = 0; s < 4; s++) {
        int kbx = kbase + ((l31 * 128 + half * 16 + s * 32) ^ ((l31 & 7) << 4));
        bf16x8 kf = *(const bf16x8*)((char*)smem + kbx);
        sacc = __builtin_amdgcn_mfma_f32_32x32x16_bf16(kf, qf[s], sacc, 0, 0, 0);
      }
      __builtin_amdgcn_s_setprio(0);

      float t0m = fmaxf(fmaxf(sacc[0], sacc[1]), sacc[2]);
      float t1m = fmaxf(fmaxf(sacc[3], sacc[4]), sacc[5]);
      float t2m = fmaxf(fmaxf(sacc[6], sacc[7]), sacc[8]);
      float t3m = fmaxf(fmaxf(sacc[9], sacc[10]), sacc[11]);
      float t4m = fmaxf(fmaxf(sacc[12], sacc[13]), sacc[14]);
      float tmax = fmaxf(fmaxf(fmaxf(t0m, t1m), fmaxf(t2m, t3m)), fmaxf(t4m, sacc[15]));
      tmax = fmaxf(tmax, __shfl_xor(tmax, 32));
      if (__any(tmax > mrun + 8.f)) {
        float mnew = fmaxf(mrun, tmax);
        float fac = __builtin_amdgcn_exp2f(mrun - mnew);
        mrun = mnew;
        lsum *= fac;
#pragma unroll
        for (int i = 0; i < 2; i++)
#pragma unroll
          for (int r = 0; r < 16; r++) oacc[i][r] *= fac;
      }
      float p[16];
#pragma unroll
      for (int r = 0; r < 16; r++) p[r] = __builtin_amdgcn_exp2f(sacc[r] - mrun);
      float s0s = (p[0] + p[1]) + (p[2] + p[3]);
      float s1s = (p[4] + p[5]) + (p[6] + p[7]);
      float s2s = (p[8] + p[9]) + (p[10] + p[11]);
      float s3s = (p[12] + p[13]) + (p[14] + p[15]);
      float tsum = (s0s + s1s) + (s2s + s3s);
      tsum += __shfl_xor(tsum, 32);
      lsum += tsum;

      u32 xs[8], px[8];
#pragma unroll
      for (int i = 0; i < 8; i++)
        asm("v_cvt_pk_bf16_f32 %0, %1, %2" : "=v"(xs[i]) : "v"(p[2 * i]), "v"(p[2 * i + 1]));
#pragma unroll
      for (int i = 0; i < 8; i++) px[i] = (u32)__shfl_xor((int)xs[i], 32);
      u32 Bk[2][4];
      Bk[0][0] = half ? px[2] : xs[0];
      Bk[0][1] = half ? px[3] : xs[1];
      Bk[0][2] = half ? xs[2] : px[0];
      Bk[0][3] = half ? xs[3] : px[1];
      Bk[1][0] = half ? px[6] : xs[4];
      Bk[1][1] = half ? px[7] : xs[5];
      Bk[1][2] = half ? xs[6] : px[4];
      Bk[1][3] = half ? xs[7] : px[5];

      int vro = vtb + l31 * 80 + ((l31 >> 3) << 4) + half * 16;
      __builtin_amdgcn_s_setprio(1);
#pragma unroll
      for (int hdf = 0; hdf < 2; hdf++) {
#pragma unroll
        for (int ks = 0; ks < 2; ks++) {
          bf16x8 vf = *(const bf16x8*)((const char*)smem + vro + hdf * 2624 + ks * 32);  // 2624 = 32*80+64
          uint4 u4;
          u4.x = Bk[ks][0]; u4.y = Bk[ks][1]; u4.z = Bk[ks][2]; u4.w = Bk[ks][3];
          bf16x8 pb = __builtin_bit_cast(bf16x8, u4);
          oacc[hdf] = __builtin_amdgcn_mfma_f32_32x32x16_bf16(vf, pb, oacc[hdf], 0, 0, 0);
        }
      }
      __builtin_amdgcn_s_setprio(0);
    }
  }

  __syncthreads();
  float inv = 1.f / lsum;
#pragma unroll
  for (int hdf = 0; hdf < 2; hdf++) {
#pragma unroll
    for (int a = 0; a < 4; a++) {
      float f0 = oacc[hdf][4 * a] * inv, f1 = oacc[hdf][4 * a + 1] * inv;
      float f2 = oacc[hdf][4 * a + 2] * inv, f3 = oacc[hdf][4 * a + 3] * inv;
      uint2 o;
      asm("v_cvt_pk_bf16_f32 %0, %1, %2" : "=v"(o.x) : "v"(f0), "v"(f1));
      asm("v_cvt_pk_bf16_f32 %0, %1, %2" : "=v"(o.y) : "v"(f2), "v"(f3));
      int off = wv * 4096 + l31 * 128 + ((16 * a + 8 * half + 64 * hdf) ^ ((l31 & 7) << 4));
      *(uint2*)((char*)smem + off) = o;
    }
  }
  __syncthreads();
#pragma unroll
  for (int it = 0; it < 4; it++) {
    int byteo = (tid + it * 512) * 16;
    int row = byteo >> 7;
    int colb = byteo & 127;
    uint4 vvv = *(const uint4*)((const char*)smem + row * 128 + (colb ^ ((row & 7) << 4)));
    *(uint4*)(ao + ((size_t)(b * T_ + t0 + row)) * D_ + h * 64 + (colb >> 1)) = vvv;
  }
}

extern "C" void kernel_launch(void* const* d_in, const int* in_sizes, int n_in,
                              void* d_out, int out_size, void* d_ws, size_t ws_size,
                              hipStream_t stream) {
  (void)in_sizes; (void)n_in; (void)out_size; (void)ws_size;
  const float* query = (const float*)d_in[0];
  const float* enc = (const float*)d_in[1];
  const float* glob = (const float*)d_in[2];
  const float* qw = (const float*)d_in[3];
  const float* qb = (const float*)d_in[4];
  const float* kw = (const float*)d_in[5];
  const float* kb = (const float*)d_in[6];
  const float* vw = (const float*)d_in[7];
  const float* vb = (const float*)d_in[8];
  const float* gkw = (const float*)d_in[9];
  const float* gkb = (const float*)d_in[10];
  const float* gvw = (const float*)d_in[11];
  const float* gvb = (const float*)d_in[12];
  const float* ow = (const float*)d_in[13];
  const float* ob = (const float*)d_in[14];
  const int* rp = (const int*)d_in[15];

  const size_t NQ = (size_t)B_ * T_ * D_;   // 8388608
  const size_t NG = (size_t)B_ * G_ * D_;   // 131072
  const size_t NW = (size_t)D_ * D_;        // 1048576

  u16* ws = (u16*)d_ws;
  u16* qx = ws;                // bf16 query
  u16* ex = qx + NQ;           // bf16 encoder_out
  u16* gx = ex + NQ;           // bf16 global_tokens
  u16* wgt = gx + NG;          // 6 weights bf16 (qw,kw,vw,gkw,gvw,ow) — contiguous
  u16* q_bf = wgt + 6 * NW;    // projected q (pre-scaled by 0.125*log2e)
  u16* k_bf = q_bf + NQ;
  u16* v_bf = k_bf + NQ;       // contiguous after k_bf (fused K|V)
  u16* gk_bf = v_bf + NQ;
  u16* gv_bf = gk_bf + NG;     // contiguous after gk_bf (fused GK|GV)
  u16* ao = gv_bf + NG;        // attention output bf16 [B*T, D]

  // one fused conversion dispatch: 8192+8192+128+6*1024 = 22656 blocks
  cvt_all_kernel<<<22656, 256, 0, stream>>>(query, enc, glob, qw, kw, vw, gkw, gvw, ow, ws);

  // merged Q + K|V + GK|GV projection: 392 blocks (one scheduling round)
  proj_kernel<<<392, 512, 0, stream>>>(ex, qx, gx, wgt, qb, kb, vb, gkb, gvb, q_bf, k_bf, gk_bf);

  attn_kernel<<<dim3(NC_, H_, B_), 512, 0, stream>>>(q_bf, k_bf, v_bf, gk_bf, gv_bf, ao, rp);

  // O projection, 8-wave ring structure
  gemmO_kernel<<<256, 512, 0, stream>>>(ao, wgt + 5 * NW, ob, (float*)d_out);
}